// Round 12
// baseline (340.434 us; speedup 1.0000x reference)
//
#include <hip/hip_runtime.h>
#include <hip/hip_bf16.h>
#include <cstdint>

typedef _Float16 half2v __attribute__((ext_vector_type(2)));

#define EPB    16        // entities per bucket
#define MAXNB  1024      // max buckets (NUMENT <= 16384)
#define FPT    8         // facts per thread (consecutive -> dwordx4 loads)
#define FPB    4096      // facts per bin chunk (512 thr x FPT)
#define SORTCAP 4608     // gather LDS payload capacity (u32 -> 18 KB)
#define CPT    9         // ceil(SORTCAP/512)
#define GRID   512       // fused grid: 2 blocks/CU guaranteed co-resident
#define OVFCAP 65536     // overflow list capacity (512 KB)

// payload u32: [31:28]=local entity (4b) | [27:16]=rel (12b, R<4096) | [15:0]=fp16(val)
// overflow uint2: x = (bucket<<16) | (le<<12) | rel, y = fp32(val) bits

// ---------------------------------------------------------------------------
// Device spin barrier. SAFE because GRID=512 blocks x 512 thr are provably
// co-resident (threads cap 4 blocks/CU, LDS 18.6KB -> 8/CU, launch_bounds
// caps VGPR for >=4 waves/SIMD; 512 = 2/CU, 2x margin). Device-scope fence +
// atomic arrive + acquire spin per Guideline 16. Bounded spin: never hangs.
// ---------------------------------------------------------------------------
__device__ __forceinline__ void grid_barrier(int* bar, int nblk) {
    __syncthreads();
    if (threadIdx.x == 0) {
        __threadfence();                       // flush my stores device-wide
        atomicAdd(bar, 1);                     // arrive (device scope)
        long long guard = 0;
        while (__hip_atomic_load(bar, __ATOMIC_ACQUIRE,
                                 __HIP_MEMORY_SCOPE_AGENT) < nblk) {
            __builtin_amdgcn_s_sleep(8);
            if (++guard > 200000000LL) break;  // ~>100ms safety valve
        }
        __threadfence();
    }
    __syncthreads();
}

// ---------------------------------------------------------------------------
// Fused kernel: phase1 = bin (+ rwb table, overlapped) ; barrier ; phase2 =
// gather. Inner structures are r11's proven ones, byte-comparable. Spill path
// replaced by an exact overflow list -> no out pre-zero, no sp read.
// ---------------------------------------------------------------------------
__global__ __launch_bounds__(512, 4) void fused_kernel(
    const int* __restrict__ heads, const int* __restrict__ tails,
    const int* __restrict__ rels, const float* __restrict__ val,
    const float* __restrict__ relf, const float* __restrict__ W,
    const float* __restrict__ bias,
    _Float16* __restrict__ rwb, int* __restrict__ gcnt,
    int* __restrict__ bar, int* __restrict__ ovfcnt, uint2* __restrict__ ovf,
    unsigned* __restrict__ slots, float* __restrict__ out,
    int E, int R, int NB, int CAPB, int NUMENT)
{
    __shared__ union {
        struct { int cnt[MAXNB]; int gbase[MAXNB]; } bin;        // 8 KB
        struct { unsigned se[SORTCAP]; int cnt[EPB]; int basep[EPB]; } gat; // 18.6 KB
    } sh;
    const int t = threadIdx.x;

    // ================= phase 1a: bin =================
    for (long long cb = blockIdx.x; cb * FPB < (long long)E; cb += GRID) {
        for (int k = t; k < NB; k += 512) sh.bin.cnt[k] = 0;
        __syncthreads();

        const int i0 = (int)(cb * FPB) + t * FPT;
        unsigned payT[FPT], payH[FPT], prT[FPT], prH[FPT];
#pragma unroll
        for (int u = 0; u < FPT; ++u) { prT[u] = 0xFFFFFFFFu; prH[u] = 0xFFFFFFFFu; }

        int tl[FPT], hd[FPT], rr[FPT];
        float vv[FPT];
        int nval = 0;
        if (i0 + FPT <= E) {
            *reinterpret_cast<int4*>(&tl[0]) = *reinterpret_cast<const int4*>(tails + i0);
            *reinterpret_cast<int4*>(&tl[4]) = *reinterpret_cast<const int4*>(tails + i0 + 4);
            *reinterpret_cast<int4*>(&hd[0]) = *reinterpret_cast<const int4*>(heads + i0);
            *reinterpret_cast<int4*>(&hd[4]) = *reinterpret_cast<const int4*>(heads + i0 + 4);
            *reinterpret_cast<int4*>(&rr[0]) = *reinterpret_cast<const int4*>(rels + i0);
            *reinterpret_cast<int4*>(&rr[4]) = *reinterpret_cast<const int4*>(rels + i0 + 4);
            *reinterpret_cast<float4*>(&vv[0]) = *reinterpret_cast<const float4*>(val + i0);
            *reinterpret_cast<float4*>(&vv[4]) = *reinterpret_cast<const float4*>(val + i0 + 4);
            nval = FPT;
        } else {
#pragma unroll
            for (int u = 0; u < FPT; ++u) {
                const int i = i0 + u;
                if (i < E) {
                    tl[u] = tails[i]; hd[u] = heads[i];
                    rr[u] = rels[i];  vv[u] = val[i];
                    nval = u + 1;
                }
            }
        }
#pragma unroll
        for (int u = 0; u < FPT; ++u) {
            if (u < nval) {
                const unsigned hv =
                    (unsigned)__builtin_bit_cast(unsigned short, (_Float16)vv[u]);
                const int bt = tl[u] >> 4, bh = hd[u] >> 4;      // EPB = 16
                payT[u] = ((unsigned)(tl[u] & 15) << 28) | ((unsigned)rr[u] << 16) | hv;
                payH[u] = ((unsigned)(hd[u] & 15) << 28) | ((unsigned)rr[u] << 16) | hv;
                const int rt = atomicAdd(&sh.bin.cnt[bt], 1);
                const int rh = atomicAdd(&sh.bin.cnt[bh], 1);
                prT[u] = ((unsigned)bt << 16) | (unsigned)rt;
                prH[u] = ((unsigned)bh << 16) | (unsigned)rh;
            }
        }
        __syncthreads();
        for (int k = t; k < NB; k += 512) {
            const int c = sh.bin.cnt[k];
            sh.bin.gbase[k] = c ? atomicAdd(&gcnt[k], c) : 0;    // 1 atomic/bucket/chunk
        }
        __syncthreads();
#pragma unroll
        for (int u = 0; u < FPT; ++u) {
            if (prT[u] != 0xFFFFFFFFu) {
                {
                    const int b1 = (int)(prT[u] >> 16);
                    const int pos = sh.bin.gbase[b1] + (int)(prT[u] & 0xFFFFu);
                    if (pos < CAPB) slots[(size_t)b1 * CAPB + pos] = payT[u];
                    else {
                        const int op = atomicAdd(ovfcnt, 1);
                        if (op < OVFCAP) {
                            uint2 o;
                            o.x = ((unsigned)b1 << 16) | ((payT[u] >> 28) << 12) |
                                  ((payT[u] >> 16) & 0xFFFu);
                            o.y = __float_as_uint(vv[u]);
                            ovf[op] = o;
                        }
                    }
                }
                {
                    const int b1 = (int)(prH[u] >> 16);
                    const int pos = sh.bin.gbase[b1] + (int)(prH[u] & 0xFFFFu);
                    if (pos < CAPB) slots[(size_t)b1 * CAPB + pos] = payH[u];
                    else {
                        const int op = atomicAdd(ovfcnt, 1);
                        if (op < OVFCAP) {
                            uint2 o;
                            o.x = ((unsigned)b1 << 16) | ((payH[u] >> 28) << 12) |
                                  ((payH[u] >> 16) & 0xFFFu);
                            o.y = __float_as_uint(vv[u]);
                            ovf[op] = o;
                        }
                    }
                }
            }
        }
        __syncthreads();
    }

    // ================= phase 1b: rwb table (overlaps bin across blocks) ====
    for (int r4 = blockIdx.x; r4 * 4 < R; r4 += GRID) {
        const int row = r4 * 4 + (t >> 7);       // 4 rows per block-iteration
        const int col = t & 127;
        if (row < R) {
            const float4* rp = reinterpret_cast<const float4*>(relf + (size_t)row * 128);
            const float4* wp = reinterpret_cast<const float4*>(W + (size_t)col * 128);
            float acc = 0.f;
#pragma unroll
            for (int i = 0; i < 32; ++i) {
                float4 a = rp[i], w = wp[i];
                acc += a.x * w.x + a.y * w.y + a.z * w.z + a.w * w.w;
            }
            rwb[(size_t)row * 128 + col] = (_Float16)(acc + bias[col]);
        }
    }

    // ================= barrier =================
    grid_barrier(bar, GRID);

    // ================= phase 2: gather =================
    const int novf = min(__hip_atomic_load(ovfcnt, __ATOMIC_RELAXED,
                                           __HIP_MEMORY_SCOPE_AGENT), OVFCAP);
    const int wv = t >> 6, lane = t & 63;
    const int loff = lane * 2;

    for (int bk = blockIdx.x; bk < NB; bk += GRID) {
        __syncthreads();
        if (t < EPB) sh.gat.cnt[t] = 0;
        __syncthreads();

        int deg = gcnt[bk];
        if (deg > CAPB) deg = CAPB;
        const unsigned* sl = slots + (size_t)bk * CAPB;

        // Phase A: coalesced load, LDS rank, hold in regs, sorted placement
        unsigned e[CPT];
        int rk[CPT];
#pragma unroll
        for (int u = 0; u < CPT; ++u) {
            const int k = t + u * 512;
            rk[u] = -1;
            if (k < deg) {
                e[u] = sl[k];
                rk[u] = atomicAdd(&sh.gat.cnt[(int)(e[u] >> 28)], 1);
            }
        }
        __syncthreads();
        if (t == 0) {
            int s = 0;
#pragma unroll
            for (int i = 0; i < EPB; ++i) { sh.gat.basep[i] = s; s += sh.gat.cnt[i]; }
        }
        __syncthreads();
#pragma unroll
        for (int u = 0; u < CPT; ++u)
            if (rk[u] >= 0) sh.gat.se[sh.gat.basep[(int)(e[u] >> 28)] + rk[u]] = e[u];
        __syncthreads();

        // Phase B: 8 waves x 2 entities; r11's proven scalarized loop
#pragma unroll
        for (int ei = 0; ei < 2; ++ei) {
            const int le = wv * 2 + ei;
            const int vent = bk * EPB + le;
            const int s0 = sh.gat.basep[le], c = sh.gat.cnt[le];
            float a0 = 0.f, a1 = 0.f;
            int j = 0;
            for (; j + 8 <= c; j += 8) {
                uint2 qp[4];
#pragma unroll
                for (int u = 0; u < 4; ++u)
                    qp[u] = *reinterpret_cast<const uint2*>(&sh.gat.se[s0 + j + 2 * u]);
                unsigned qs[8];
#pragma unroll
                for (int u = 0; u < 4; ++u) {
                    qs[2 * u]     = __builtin_amdgcn_readfirstlane(qp[u].x);
                    qs[2 * u + 1] = __builtin_amdgcn_readfirstlane(qp[u].y);
                }
                unsigned rw[8];
#pragma unroll
                for (int u = 0; u < 8; ++u) {
                    const _Float16* rowp = rwb + (size_t)((qs[u] >> 16) & 0xFFFu) * 128;
                    rw[u] = *reinterpret_cast<const unsigned*>(rowp + loff);
                }
#pragma unroll
                for (int u = 0; u < 8; ++u) {
                    asm("v_fma_mix_f32 %[d], %[s0], %[s1], %[d] op_sel:[0,0,0] op_sel_hi:[1,1,0]"
                        : [d]"+v"(a0) : [s0]"s"(qs[u]), [s1]"v"(rw[u]));
                    asm("v_fma_mix_f32 %[d], %[s0], %[s1], %[d] op_sel:[0,1,0] op_sel_hi:[1,1,0]"
                        : [d]"+v"(a1) : [s0]"s"(qs[u]), [s1]"v"(rw[u]));
                }
            }
            for (; j < c; ++j) {
                const unsigned q = sh.gat.se[s0 + j];
                const unsigned qs = __builtin_amdgcn_readfirstlane(q);
                const _Float16* rowp = rwb + (size_t)((qs >> 16) & 0xFFFu) * 128;
                const unsigned rwv = *reinterpret_cast<const unsigned*>(rowp + loff);
                asm("v_fma_mix_f32 %[d], %[s0], %[s1], %[d] op_sel:[0,0,0] op_sel_hi:[1,1,0]"
                    : [d]"+v"(a0) : [s0]"s"(qs), [s1]"v"(rwv));
                asm("v_fma_mix_f32 %[d], %[s0], %[s1], %[d] op_sel:[0,1,0] op_sel_hi:[1,1,0]"
                    : [d]"+v"(a1) : [s0]"s"(qs), [s1]"v"(rwv));
            }
            // exact overflow contributions (novf == 0 in practice)
            for (int k = 0; k < novf; ++k) {
                const uint2 o = ovf[k];
                if ((int)(o.x >> 16) == bk && (int)((o.x >> 12) & 15u) == le) {
                    const int orel = (int)(o.x & 0xFFFu);
                    const float ov = __uint_as_float(o.y);
                    const unsigned orw = *reinterpret_cast<const unsigned*>(
                        rwb + (size_t)orel * 128 + loff);
                    const half2v oh = __builtin_bit_cast(half2v, orw);
                    a0 += ov * (float)oh[0];
                    a1 += ov * (float)oh[1];
                }
            }
            if (vent < NUMENT) {
                float* op = out + (size_t)vent * 128 + loff;
                float2 o2;
                o2.x = fmaxf(a0, 0.f);
                o2.y = fmaxf(a1, 0.f);
                *reinterpret_cast<float2*>(op) = o2;   // pure store: no pre-zero, no sp read
            }
        }
    }
}

// ---------------------------------------------------------------------------
// Fallback path (ws too small / shape out of range): direct vector scatter.
// ---------------------------------------------------------------------------
__global__ void rwb_f32_kernel(const float* __restrict__ rel, const float* __restrict__ W,
                               const float* __restrict__ b, float* __restrict__ rwb, int R) {
    const int k = blockIdx.x;
    const int n = threadIdx.x;
    __shared__ float relk[128];
    relk[n] = rel[(size_t)k * 128 + n];
    __syncthreads();
    const float4* w4 = reinterpret_cast<const float4*>(W + (size_t)n * 128);
    const float4* r4 = reinterpret_cast<const float4*>(relk);
    float acc = 0.f;
#pragma unroll
    for (int i = 0; i < 32; ++i) {
        float4 a = r4[i], w = w4[i];
        acc += a.x * w.x + a.y * w.y + a.z * w.z + a.w * w.w;
    }
    rwb[(size_t)k * 128 + n] = acc + b[n];
}

__global__ void scatter_vec_kernel(const int* __restrict__ heads, const int* __restrict__ tails,
                                   const int* __restrict__ rels, const float* __restrict__ val,
                                   const float* __restrict__ rwb, float* __restrict__ out,
                                   long long nitems) {
    const long long i = (long long)blockIdx.x * blockDim.x + threadIdx.x;
    if (i >= nitems) return;
    const int e = (int)(i >> 5);
    const int c = (int)(i & 31) * 4;
    const float v = val[e];
    float4 rw = *reinterpret_cast<const float4*>(rwb + (size_t)rels[e] * 128 + c);
    float* pt = out + (size_t)tails[e] * 128 + c;
    float* ph = out + (size_t)heads[e] * 128 + c;
    unsafeAtomicAdd(pt + 0, v * rw.x); unsafeAtomicAdd(pt + 1, v * rw.y);
    unsafeAtomicAdd(pt + 2, v * rw.z); unsafeAtomicAdd(pt + 3, v * rw.w);
    unsafeAtomicAdd(ph + 0, v * rw.x); unsafeAtomicAdd(ph + 1, v * rw.y);
    unsafeAtomicAdd(ph + 2, v * rw.z); unsafeAtomicAdd(ph + 3, v * rw.w);
}

__global__ void relu_kernel(float* __restrict__ out, int n4) {
    const int i = blockIdx.x * blockDim.x + threadIdx.x;
    if (i >= n4) return;
    float4* p = reinterpret_cast<float4*>(out) + i;
    float4 v = *p;
    v.x = fmaxf(v.x, 0.f); v.y = fmaxf(v.y, 0.f);
    v.z = fmaxf(v.z, 0.f); v.w = fmaxf(v.w, 0.f);
    *p = v;
}

// ---------------------------------------------------------------------------
extern "C" void kernel_launch(void* const* d_in, const int* in_sizes, int n_in,
                              void* d_out, int out_size, void* d_ws, size_t ws_size,
                              hipStream_t stream) {
    // inputs: 0 local_entity [B*M] (shape only), 1 heads [E], 2 tails [E],
    //         3 rels [E], 4 val [E], 5 rel_features [R*D], 6 W [D*D], 7 b [D]
    const int* heads = (const int*)d_in[1];
    const int* tails = (const int*)d_in[2];
    const int* rels  = (const int*)d_in[3];
    const float* val  = (const float*)d_in[4];
    const float* relf = (const float*)d_in[5];
    const float* W    = (const float*)d_in[6];
    const float* b    = (const float*)d_in[7];
    float* out = (float*)d_out;

    const int NUMENT = in_sizes[0];          // 16000
    const int E      = in_sizes[1];          // 2,000,000
    const int D      = in_sizes[7];          // 128
    const int R      = in_sizes[5] / D;      // 2000

    const int NB = (NUMENT + EPB - 1) / EPB; // 1000 buckets
    const long long mean = (2LL * E * EPB) / (NUMENT > 0 ? NUMENT : 1);
    int CAPB = (int)(mean + mean / 16 + 256);

    // ws layout: rwb | ctrl { gcnt[NB], bar, ovfcnt } | ovf[OVFCAP] | slots
    const size_t rwb_bytes = (size_t)R * D * sizeof(_Float16);          // 512 KB
    const size_t off_ctrl  = (rwb_bytes + 255) & ~(size_t)255;
    const size_t ctrl_b    = (size_t)(NB + 2) * sizeof(int);
    const size_t off_ovf   = (off_ctrl + ctrl_b + 255) & ~(size_t)255;
    const size_t ovf_b     = (size_t)OVFCAP * sizeof(uint2);            // 512 KB
    const size_t off_slots = (off_ovf + ovf_b + 255) & ~(size_t)255;
    const size_t slots_b   = (size_t)NB * CAPB * sizeof(unsigned);      // ~18 MB

    if (NB <= MAXNB && R < 4096 && CAPB <= SORTCAP &&
        ws_size >= off_slots + slots_b) {
        _Float16* rwb   = (_Float16*)d_ws;
        int* gcnt       = (int*)((char*)d_ws + off_ctrl);
        int* bar        = gcnt + NB;
        int* ovfcnt     = gcnt + NB + 1;
        uint2* ovf      = (uint2*)((char*)d_ws + off_ovf);
        unsigned* slots = (unsigned*)((char*)d_ws + off_slots);

        hipMemsetAsync(gcnt, 0, ctrl_b, stream);     // gcnt + bar + ovfcnt
        fused_kernel<<<GRID, 512, 0, stream>>>(
            heads, tails, rels, val, relf, W, b,
            rwb, gcnt, bar, ovfcnt, ovf, slots, out,
            E, R, NB, CAPB, NUMENT);
    } else {
        // fallback: accumulate directly into out (slow but small-ws safe)
        float* rwb = (float*)d_ws;           // R*D fp32 (~1 MB)
        hipMemsetAsync(out, 0, (size_t)out_size * sizeof(float), stream);
        rwb_f32_kernel<<<R, 128, 0, stream>>>(relf, W, b, rwb, R);
        const long long items = (long long)E * 32;
        scatter_vec_kernel<<<(unsigned)((items + 255) / 256), 256, 0, stream>>>(
            heads, tails, rels, val, rwb, out, items);
        relu_kernel<<<(out_size / 4 + 255) / 256, 256, 0, stream>>>(out, out_size / 4);
    }
}

// Round 13
// 187.799 us; speedup vs baseline: 1.8128x; 1.8128x over previous
//
#include <hip/hip_runtime.h>
#include <hip/hip_bf16.h>
#include <cstdint>

typedef _Float16 half2v __attribute__((ext_vector_type(2)));

#define EPB   16        // entities per bucket
#define MAXNB 1024      // max buckets for bin LDS histogram (NUMENT <= 16384)
#define FPB   4096      // facts per bin-block (1024 thr x FPT 4) -> 489 blocks (~2/CU)
#define FPT   4         // facts per thread (CONSECUTIVE -> dwordx4 loads)
#define SORTCAP 4608    // gather LDS payload capacity (u32 -> 18 KB)
#define CPT   9         // ceil(SORTCAP / 512) register-held entries per thread
#define OVFCAP 65536    // overflow list capacity (512 KB; statistically unreachable)

// payload u32: [31:28]=local entity (4b) | [27:16]=rel (12b, R<4096) | [15:0]=fp16(val)
// overflow uint2: x = (bucket<<16) | (le<<12) | rel, y = fp32(val) bits

// ---------------------------------------------------------------------------
// Kernel 1: bin endpoints into per-bucket lists (bucket = entity >> 4), then
// grid-strided RWB table build appended (rwb = relf @ W^T + b, fp16 rows).
// Bin inner structure is r11's exact proven one (vectorized dwordx4 fact
// loads). rwb work hides in bin's latency shadow (different pipes: VALU/L2
// vs DS-atomic/scatter-store). Spill -> overflow list (r12-proven): no out
// pre-zero needed anywhere.
// ---------------------------------------------------------------------------
__global__ __launch_bounds__(1024) void bin_rwb_kernel(
    const int* __restrict__ heads, const int* __restrict__ tails,
    const int* __restrict__ rels, const float* __restrict__ val,
    const float* __restrict__ relf, const float* __restrict__ W,
    const float* __restrict__ bias, _Float16* __restrict__ rwb,
    int* __restrict__ gcnt, int* __restrict__ ovfcnt, uint2* __restrict__ ovf,
    unsigned* __restrict__ slots,
    int E, int R, int NB, int CAPB) {
    __shared__ int cnt[MAXNB];
    __shared__ int gbase[MAXNB];
    const int t = threadIdx.x;
    for (int k = t; k < NB; k += 1024) cnt[k] = 0;
    __syncthreads();

    const int i0 = blockIdx.x * FPB + t * FPT;
    unsigned payT[FPT], payH[FPT], prT[FPT], prH[FPT];
#pragma unroll
    for (int u = 0; u < FPT; ++u) { prT[u] = 0xFFFFFFFFu; prH[u] = 0xFFFFFFFFu; }

    int tl[FPT], hd[FPT], rr[FPT];
    float vv[FPT];
    int nval = 0;
    if (i0 + FPT <= E) {
        const int4 T  = *reinterpret_cast<const int4*>(tails + i0);
        const int4 H  = *reinterpret_cast<const int4*>(heads + i0);
        const int4 Rv = *reinterpret_cast<const int4*>(rels + i0);
        const float4 Vv = *reinterpret_cast<const float4*>(val + i0);
        tl[0] = T.x;  tl[1] = T.y;  tl[2] = T.z;  tl[3] = T.w;
        hd[0] = H.x;  hd[1] = H.y;  hd[2] = H.z;  hd[3] = H.w;
        rr[0] = Rv.x; rr[1] = Rv.y; rr[2] = Rv.z; rr[3] = Rv.w;
        vv[0] = Vv.x; vv[1] = Vv.y; vv[2] = Vv.z; vv[3] = Vv.w;
        nval = FPT;
    } else {
#pragma unroll
        for (int u = 0; u < FPT; ++u) {
            const int i = i0 + u;
            if (i < E) {
                tl[u] = tails[i]; hd[u] = heads[i];
                rr[u] = rels[i];  vv[u] = val[i];
                nval = u + 1;
            }
        }
    }
#pragma unroll
    for (int u = 0; u < FPT; ++u) {
        if (u < nval) {
            const unsigned hv =
                (unsigned)__builtin_bit_cast(unsigned short, (_Float16)vv[u]);
            const int bt = tl[u] >> 4, bh = hd[u] >> 4;      // EPB = 16
            payT[u] = ((unsigned)(tl[u] & 15) << 28) | ((unsigned)rr[u] << 16) | hv;
            payH[u] = ((unsigned)(hd[u] & 15) << 28) | ((unsigned)rr[u] << 16) | hv;
            const int rt = atomicAdd(&cnt[bt], 1);           // LDS int rank (native)
            const int rh = atomicAdd(&cnt[bh], 1);
            prT[u] = ((unsigned)bt << 16) | (unsigned)rt;    // rank < 16384 fits
            prH[u] = ((unsigned)bh << 16) | (unsigned)rh;
        }
    }
    __syncthreads();
    for (int k = t; k < NB; k += 1024) {
        const int c = cnt[k];
        gbase[k] = c ? atomicAdd(&gcnt[k], c) : 0;           // 1 atomic / bucket / block
    }
    __syncthreads();
#pragma unroll
    for (int u = 0; u < FPT; ++u) {
        if (prT[u] != 0xFFFFFFFFu) {
            {
                const int b1 = (int)(prT[u] >> 16);
                const int pos = gbase[b1] + (int)(prT[u] & 0xFFFFu);
                if (pos < CAPB) slots[(size_t)b1 * CAPB + pos] = payT[u];
                else {
                    const int op = atomicAdd(ovfcnt, 1);
                    if (op < OVFCAP) {
                        uint2 o;
                        o.x = ((unsigned)b1 << 16) | ((payT[u] >> 28) << 12) |
                              ((payT[u] >> 16) & 0xFFFu);
                        o.y = __float_as_uint(vv[u]);
                        ovf[op] = o;
                    }
                }
            }
            {
                const int b1 = (int)(prH[u] >> 16);
                const int pos = gbase[b1] + (int)(prH[u] & 0xFFFFu);
                if (pos < CAPB) slots[(size_t)b1 * CAPB + pos] = payH[u];
                else {
                    const int op = atomicAdd(ovfcnt, 1);
                    if (op < OVFCAP) {
                        uint2 o;
                        o.x = ((unsigned)b1 << 16) | ((payH[u] >> 28) << 12) |
                              ((payH[u] >> 16) & 0xFFFu);
                        o.y = __float_as_uint(vv[u]);
                        ovf[op] = o;
                    }
                }
            }
        }
    }

    // ---- appended: RWB table (grid-strided, 8 rows / block-iteration) ----
    const int rsub = t >> 7;            // 0..7
    const int col  = t & 127;
    for (int row0 = blockIdx.x * 8; row0 < R; row0 += gridDim.x * 8) {
        const int row = row0 + rsub;
        if (row < R) {
            const float4* rp = reinterpret_cast<const float4*>(relf + (size_t)row * 128);
            const float4* wp = reinterpret_cast<const float4*>(W + (size_t)col * 128);
            float acc = 0.f;
#pragma unroll
            for (int i = 0; i < 32; ++i) {
                float4 a = rp[i], w = wp[i];
                acc += a.x * w.x + a.y * w.y + a.z * w.z + a.w * w.w;
            }
            rwb[(size_t)row * 128 + col] = (_Float16)(acc + bias[col]);
        }
    }
}

// ---------------------------------------------------------------------------
// Kernel 2: gather — one 512-thread block per 16-entity bucket.
// Phase A: counting sort into 18KB LDS; Phase B: r11's exact proven
// scalarized loop (ds_read2 pairs -> readfirstlane -> saddr row load ->
// v_fma_mix_f32). Changes vs r11: pure store (no sp read — spills now go via
// the exact overflow list, applied below), saving 8MB of FETCH.
// ---------------------------------------------------------------------------
__global__ __launch_bounds__(512) void gather_kernel(
    const unsigned* __restrict__ slots, const int* __restrict__ gcnt,
    const int* __restrict__ ovfcnt, const uint2* __restrict__ ovf,
    const _Float16* __restrict__ rwb, float* __restrict__ out,
    int NUMENT, int CAPB) {
    __shared__ unsigned se[SORTCAP];           // 18 KB sorted payloads
    __shared__ int cnt[EPB], basep[EPB];
    const int t = threadIdx.x;
    const int b = blockIdx.x;
    if (t < EPB) cnt[t] = 0;
    __syncthreads();

    int deg = gcnt[b];
    if (deg > CAPB) deg = CAPB;        // overflow entries went to ovf list
    const unsigned* sl = slots + (size_t)b * CAPB;

    // Phase A: coalesced load, LDS rank, hold in registers, sorted placement
    unsigned e[CPT];
    int rk[CPT];
#pragma unroll
    for (int u = 0; u < CPT; ++u) {
        const int k = t + u * 512;
        rk[u] = -1;
        if (k < deg) {
            e[u] = sl[k];
            rk[u] = atomicAdd(&cnt[(int)(e[u] >> 28)], 1);
        }
    }
    __syncthreads();
    if (t == 0) {
        int s = 0;
#pragma unroll
        for (int i = 0; i < EPB; ++i) { basep[i] = s; s += cnt[i]; }
    }
    __syncthreads();
#pragma unroll
    for (int u = 0; u < CPT; ++u)
        if (rk[u] >= 0) se[basep[(int)(e[u] >> 28)] + rk[u]] = e[u];
    __syncthreads();

    const int novf = min(*ovfcnt, OVFCAP);     // 0 in practice

    // Phase B: 8 waves x 2 entities; scalarized, batches of 8
    const int wv = t >> 6, lane = t & 63;
    const int loff = lane * 2;                 // _Float16 element offset in row
#pragma unroll
    for (int ei = 0; ei < 2; ++ei) {
        const int le = wv * 2 + ei;
        const int vent = b * EPB + le;
        const int s0 = basep[le], c = cnt[le];
        float a0 = 0.f, a1 = 0.f;
        int j = 0;
        for (; j + 8 <= c; j += 8) {
            uint2 qp[4];
#pragma unroll
            for (int u = 0; u < 4; ++u)        // ds_read2_b32: 2 payloads / issue
                qp[u] = *reinterpret_cast<const uint2*>(&se[s0 + j + 2 * u]);
            unsigned qs[8];
#pragma unroll
            for (int u = 0; u < 4; ++u) {
                qs[2 * u]     = __builtin_amdgcn_readfirstlane(qp[u].x);
                qs[2 * u + 1] = __builtin_amdgcn_readfirstlane(qp[u].y);
            }
            unsigned rw[8];
#pragma unroll
            for (int u = 0; u < 8; ++u) {
                const _Float16* rowp = rwb + (size_t)((qs[u] >> 16) & 0xFFFu) * 128;
                rw[u] = *reinterpret_cast<const unsigned*>(rowp + loff);  // saddr + v_lane
            }
#pragma unroll
            for (int u = 0; u < 8; ++u) {
                asm("v_fma_mix_f32 %[d], %[s0], %[s1], %[d] op_sel:[0,0,0] op_sel_hi:[1,1,0]"
                    : [d]"+v"(a0) : [s0]"s"(qs[u]), [s1]"v"(rw[u]));
                asm("v_fma_mix_f32 %[d], %[s0], %[s1], %[d] op_sel:[0,1,0] op_sel_hi:[1,1,0]"
                    : [d]"+v"(a1) : [s0]"s"(qs[u]), [s1]"v"(rw[u]));
            }
        }
        for (; j < c; ++j) {
            const unsigned q = se[s0 + j];
            const unsigned qs = __builtin_amdgcn_readfirstlane(q);
            const _Float16* rowp = rwb + (size_t)((qs >> 16) & 0xFFFu) * 128;
            const unsigned rwv = *reinterpret_cast<const unsigned*>(rowp + loff);
            asm("v_fma_mix_f32 %[d], %[s0], %[s1], %[d] op_sel:[0,0,0] op_sel_hi:[1,1,0]"
                : [d]"+v"(a0) : [s0]"s"(qs), [s1]"v"(rwv));
            asm("v_fma_mix_f32 %[d], %[s0], %[s1], %[d] op_sel:[0,1,0] op_sel_hi:[1,1,0]"
                : [d]"+v"(a1) : [s0]"s"(qs), [s1]"v"(rwv));
        }
        // exact overflow contributions (novf == 0 in practice)
        for (int k = 0; k < novf; ++k) {
            const uint2 o = ovf[k];
            if ((int)(o.x >> 16) == b && (int)((o.x >> 12) & 15u) == le) {
                const int orel = (int)(o.x & 0xFFFu);
                const float ov = __uint_as_float(o.y);
                const unsigned orw = *reinterpret_cast<const unsigned*>(
                    rwb + (size_t)orel * 128 + loff);
                const half2v oh = __builtin_bit_cast(half2v, orw);
                a0 += ov * (float)oh[0];
                a1 += ov * (float)oh[1];
            }
        }
        if (vent < NUMENT) {
            float* op = out + (size_t)vent * 128 + loff;
            float2 o2;
            o2.x = fmaxf(a0, 0.f);
            o2.y = fmaxf(a1, 0.f);
            *reinterpret_cast<float2*>(op) = o2;   // pure store: no pre-zero, no sp read
        }
    }
}

// ---------------------------------------------------------------------------
// Fallback path (ws too small / shape out of range): direct vector scatter.
// ---------------------------------------------------------------------------
__global__ void rwb_f32_kernel(const float* __restrict__ rel, const float* __restrict__ W,
                               const float* __restrict__ b, float* __restrict__ rwb, int R) {
    const int k = blockIdx.x;
    const int n = threadIdx.x;
    __shared__ float relk[128];
    relk[n] = rel[(size_t)k * 128 + n];
    __syncthreads();
    const float4* w4 = reinterpret_cast<const float4*>(W + (size_t)n * 128);
    const float4* r4 = reinterpret_cast<const float4*>(relk);
    float acc = 0.f;
#pragma unroll
    for (int i = 0; i < 32; ++i) {
        float4 a = r4[i], w = w4[i];
        acc += a.x * w.x + a.y * w.y + a.z * w.z + a.w * w.w;
    }
    rwb[(size_t)k * 128 + n] = acc + b[n];
}

__global__ void scatter_vec_kernel(const int* __restrict__ heads, const int* __restrict__ tails,
                                   const int* __restrict__ rels, const float* __restrict__ val,
                                   const float* __restrict__ rwb, float* __restrict__ out,
                                   long long nitems) {
    const long long i = (long long)blockIdx.x * blockDim.x + threadIdx.x;
    if (i >= nitems) return;
    const int e = (int)(i >> 5);
    const int c = (int)(i & 31) * 4;
    const float v = val[e];
    float4 rw = *reinterpret_cast<const float4*>(rwb + (size_t)rels[e] * 128 + c);
    float* pt = out + (size_t)tails[e] * 128 + c;
    float* ph = out + (size_t)heads[e] * 128 + c;
    unsafeAtomicAdd(pt + 0, v * rw.x); unsafeAtomicAdd(pt + 1, v * rw.y);
    unsafeAtomicAdd(pt + 2, v * rw.z); unsafeAtomicAdd(pt + 3, v * rw.w);
    unsafeAtomicAdd(ph + 0, v * rw.x); unsafeAtomicAdd(ph + 1, v * rw.y);
    unsafeAtomicAdd(ph + 2, v * rw.z); unsafeAtomicAdd(ph + 3, v * rw.w);
}

__global__ void relu_kernel(float* __restrict__ out, int n4) {
    const int i = blockIdx.x * blockDim.x + threadIdx.x;
    if (i >= n4) return;
    float4* p = reinterpret_cast<float4*>(out) + i;
    float4 v = *p;
    v.x = fmaxf(v.x, 0.f); v.y = fmaxf(v.y, 0.f);
    v.z = fmaxf(v.z, 0.f); v.w = fmaxf(v.w, 0.f);
    *p = v;
}

// ---------------------------------------------------------------------------
extern "C" void kernel_launch(void* const* d_in, const int* in_sizes, int n_in,
                              void* d_out, int out_size, void* d_ws, size_t ws_size,
                              hipStream_t stream) {
    // inputs: 0 local_entity [B*M] (shape only), 1 heads [E], 2 tails [E],
    //         3 rels [E], 4 val [E], 5 rel_features [R*D], 6 W [D*D], 7 b [D]
    const int* heads = (const int*)d_in[1];
    const int* tails = (const int*)d_in[2];
    const int* rels  = (const int*)d_in[3];
    const float* val  = (const float*)d_in[4];
    const float* relf = (const float*)d_in[5];
    const float* W    = (const float*)d_in[6];
    const float* b    = (const float*)d_in[7];
    float* out = (float*)d_out;

    const int NUMENT = in_sizes[0];          // 16000
    const int E      = in_sizes[1];          // 2,000,000
    const int D      = in_sizes[7];          // 128
    const int R      = in_sizes[5] / D;      // 2000

    const int NB = (NUMENT + EPB - 1) / EPB; // 1000 buckets
    // expected endpoints/bucket = 2E*EPB/NUMENT (=4000, sigma~63);
    // slack mean/16+256 ~ +9.6 sigma at default shape
    const long long mean = (2LL * E * EPB) / (NUMENT > 0 ? NUMENT : 1);
    int CAPB = (int)(mean + mean / 16 + 256);

    // ws layout: rwb | ctrl { gcnt[NB], ovfcnt } | ovf[OVFCAP] | slots
    const size_t rwb_bytes = (size_t)R * D * sizeof(_Float16);          // 512 KB
    const size_t off_ctrl  = (rwb_bytes + 255) & ~(size_t)255;
    const size_t ctrl_b    = (size_t)(NB + 1) * sizeof(int);
    const size_t off_ovf   = (off_ctrl + ctrl_b + 255) & ~(size_t)255;
    const size_t ovf_b     = (size_t)OVFCAP * sizeof(uint2);            // 512 KB
    const size_t off_slots = (off_ovf + ovf_b + 255) & ~(size_t)255;
    const size_t slots_b   = (size_t)NB * CAPB * sizeof(unsigned);      // ~18 MB

    if (NB <= MAXNB && R < 4096 && CAPB <= SORTCAP &&
        ws_size >= off_slots + slots_b) {
        _Float16* rwb   = (_Float16*)d_ws;
        int* gcnt       = (int*)((char*)d_ws + off_ctrl);
        int* ovfcnt     = gcnt + NB;
        uint2* ovf      = (uint2*)((char*)d_ws + off_ovf);
        unsigned* slots = (unsigned*)((char*)d_ws + off_slots);

        hipMemsetAsync(gcnt, 0, ctrl_b, stream);     // gcnt + ovfcnt (4 KB)
        bin_rwb_kernel<<<(E + FPB - 1) / FPB, 1024, 0, stream>>>(
            heads, tails, rels, val, relf, W, b, rwb,
            gcnt, ovfcnt, ovf, slots, E, R, NB, CAPB);
        gather_kernel<<<NB, 512, 0, stream>>>(
            slots, gcnt, ovfcnt, ovf, rwb, out, NUMENT, CAPB);
    } else {
        // fallback: accumulate directly into out (slow but small-ws safe)
        float* rwb = (float*)d_ws;           // R*D fp32 (~1 MB)
        hipMemsetAsync(out, 0, (size_t)out_size * sizeof(float), stream);
        rwb_f32_kernel<<<R, 128, 0, stream>>>(relf, W, b, rwb, R);
        const long long items = (long long)E * 32;
        scatter_vec_kernel<<<(unsigned)((items + 255) / 256), 256, 0, stream>>>(
            heads, tails, rels, val, rwb, out, items);
        relu_kernel<<<(out_size / 4 + 255) / 256, 256, 0, stream>>>(out, out_size / 4);
    }
}

// Round 14
// 186.137 us; speedup vs baseline: 1.8289x; 1.0089x over previous
//
#include <hip/hip_runtime.h>
#include <hip/hip_bf16.h>
#include <cstdint>

typedef _Float16 half2v __attribute__((ext_vector_type(2)));

#define EPB   16        // entities per bucket
#define MAXNB 1024      // max buckets for bin LDS histogram (NUMENT <= 16384)
#define FPB   4096      // facts per bin-block (1024 thr x FPT 4) -> 489 blocks
#define FPT   4         // facts per thread (CONSECUTIVE -> dwordx4 loads)
#define SORTCAP 4608    // gather LDS payload capacity (u32 -> 18 KB)
#define CPT   9         // ceil(SORTCAP / 512) register-held entries per thread
#define OVFCAP 65536    // overflow list capacity (512 KB; statistically unreachable)

// payload u32: [31:28]=local entity (4b) | [27:16]=rel (12b, R<4096) | [15:0]=fp16(val)
// overflow uint2: x = (bucket<<16) | (le<<12) | rel, y = fp32(val) bits

// ---------------------------------------------------------------------------
// Kernel 1: bin endpoints into per-bucket lists + appended RWB table build.
// UNCHANGED from round 13 (proven 58.8us, rwb fully hidden).
// ---------------------------------------------------------------------------
__global__ __launch_bounds__(1024) void bin_rwb_kernel(
    const int* __restrict__ heads, const int* __restrict__ tails,
    const int* __restrict__ rels, const float* __restrict__ val,
    const float* __restrict__ relf, const float* __restrict__ W,
    const float* __restrict__ bias, _Float16* __restrict__ rwb,
    int* __restrict__ gcnt, int* __restrict__ ovfcnt, uint2* __restrict__ ovf,
    unsigned* __restrict__ slots,
    int E, int R, int NB, int CAPB) {
    __shared__ int cnt[MAXNB];
    __shared__ int gbase[MAXNB];
    const int t = threadIdx.x;
    for (int k = t; k < NB; k += 1024) cnt[k] = 0;
    __syncthreads();

    const int i0 = blockIdx.x * FPB + t * FPT;
    unsigned payT[FPT], payH[FPT], prT[FPT], prH[FPT];
#pragma unroll
    for (int u = 0; u < FPT; ++u) { prT[u] = 0xFFFFFFFFu; prH[u] = 0xFFFFFFFFu; }

    int tl[FPT], hd[FPT], rr[FPT];
    float vv[FPT];
    int nval = 0;
    if (i0 + FPT <= E) {
        const int4 T  = *reinterpret_cast<const int4*>(tails + i0);
        const int4 H  = *reinterpret_cast<const int4*>(heads + i0);
        const int4 Rv = *reinterpret_cast<const int4*>(rels + i0);
        const float4 Vv = *reinterpret_cast<const float4*>(val + i0);
        tl[0] = T.x;  tl[1] = T.y;  tl[2] = T.z;  tl[3] = T.w;
        hd[0] = H.x;  hd[1] = H.y;  hd[2] = H.z;  hd[3] = H.w;
        rr[0] = Rv.x; rr[1] = Rv.y; rr[2] = Rv.z; rr[3] = Rv.w;
        vv[0] = Vv.x; vv[1] = Vv.y; vv[2] = Vv.z; vv[3] = Vv.w;
        nval = FPT;
    } else {
#pragma unroll
        for (int u = 0; u < FPT; ++u) {
            const int i = i0 + u;
            if (i < E) {
                tl[u] = tails[i]; hd[u] = heads[i];
                rr[u] = rels[i];  vv[u] = val[i];
                nval = u + 1;
            }
        }
    }
#pragma unroll
    for (int u = 0; u < FPT; ++u) {
        if (u < nval) {
            const unsigned hv =
                (unsigned)__builtin_bit_cast(unsigned short, (_Float16)vv[u]);
            const int bt = tl[u] >> 4, bh = hd[u] >> 4;      // EPB = 16
            payT[u] = ((unsigned)(tl[u] & 15) << 28) | ((unsigned)rr[u] << 16) | hv;
            payH[u] = ((unsigned)(hd[u] & 15) << 28) | ((unsigned)rr[u] << 16) | hv;
            const int rt = atomicAdd(&cnt[bt], 1);           // LDS int rank (native)
            const int rh = atomicAdd(&cnt[bh], 1);
            prT[u] = ((unsigned)bt << 16) | (unsigned)rt;    // rank < 16384 fits
            prH[u] = ((unsigned)bh << 16) | (unsigned)rh;
        }
    }
    __syncthreads();
    for (int k = t; k < NB; k += 1024) {
        const int c = cnt[k];
        gbase[k] = c ? atomicAdd(&gcnt[k], c) : 0;           // 1 atomic / bucket / block
    }
    __syncthreads();
#pragma unroll
    for (int u = 0; u < FPT; ++u) {
        if (prT[u] != 0xFFFFFFFFu) {
            {
                const int b1 = (int)(prT[u] >> 16);
                const int pos = gbase[b1] + (int)(prT[u] & 0xFFFFu);
                if (pos < CAPB) slots[(size_t)b1 * CAPB + pos] = payT[u];
                else {
                    const int op = atomicAdd(ovfcnt, 1);
                    if (op < OVFCAP) {
                        uint2 o;
                        o.x = ((unsigned)b1 << 16) | ((payT[u] >> 28) << 12) |
                              ((payT[u] >> 16) & 0xFFFu);
                        o.y = __float_as_uint(vv[u]);
                        ovf[op] = o;
                    }
                }
            }
            {
                const int b1 = (int)(prH[u] >> 16);
                const int pos = gbase[b1] + (int)(prH[u] & 0xFFFFu);
                if (pos < CAPB) slots[(size_t)b1 * CAPB + pos] = payH[u];
                else {
                    const int op = atomicAdd(ovfcnt, 1);
                    if (op < OVFCAP) {
                        uint2 o;
                        o.x = ((unsigned)b1 << 16) | ((payH[u] >> 28) << 12) |
                              ((payH[u] >> 16) & 0xFFFu);
                        o.y = __float_as_uint(vv[u]);
                        ovf[op] = o;
                    }
                }
            }
        }
    }

    // ---- appended: RWB table (grid-strided, 8 rows / block-iteration) ----
    const int rsub = t >> 7;            // 0..7
    const int col  = t & 127;
    for (int row0 = blockIdx.x * 8; row0 < R; row0 += gridDim.x * 8) {
        const int row = row0 + rsub;
        if (row < R) {
            const float4* rp = reinterpret_cast<const float4*>(relf + (size_t)row * 128);
            const float4* wp = reinterpret_cast<const float4*>(W + (size_t)col * 128);
            float acc = 0.f;
#pragma unroll
            for (int i = 0; i < 32; ++i) {
                float4 a = rp[i], w = wp[i];
                acc += a.x * w.x + a.y * w.y + a.z * w.z + a.w * w.w;
            }
            rwb[(size_t)row * 128 + col] = (_Float16)(acc + bias[col]);
        }
    }
}

// batch-of-8 for one entity: named registers, no rotation copies
#define GATHER_BATCH8(S0, J, A0, A1)                                            \
    {                                                                           \
        uint2 qp[4];                                                            \
        _Pragma("unroll")                                                       \
        for (int u = 0; u < 4; ++u)                                             \
            qp[u] = *reinterpret_cast<const uint2*>(&se[(S0) + (J) + 2 * u]);   \
        unsigned qs[8];                                                         \
        _Pragma("unroll")                                                       \
        for (int u = 0; u < 4; ++u) {                                           \
            qs[2 * u]     = __builtin_amdgcn_readfirstlane(qp[u].x);            \
            qs[2 * u + 1] = __builtin_amdgcn_readfirstlane(qp[u].y);            \
        }                                                                       \
        unsigned rw[8];                                                         \
        _Pragma("unroll")                                                       \
        for (int u = 0; u < 8; ++u) {                                           \
            const _Float16* rowp = rwb + (size_t)((qs[u] >> 16) & 0xFFFu) * 128;\
            rw[u] = *reinterpret_cast<const unsigned*>(rowp + loff);            \
        }                                                                       \
        _Pragma("unroll")                                                       \
        for (int u = 0; u < 8; ++u) {                                           \
            asm("v_fma_mix_f32 %[d], %[s0], %[s1], %[d] op_sel:[0,0,0] op_sel_hi:[1,1,0]" \
                : [d]"+v"(A0) : [s0]"s"(qs[u]), [s1]"v"(rw[u]));                \
            asm("v_fma_mix_f32 %[d], %[s0], %[s1], %[d] op_sel:[0,1,0] op_sel_hi:[1,1,0]" \
                : [d]"+v"(A1) : [s0]"s"(qs[u]), [s1]"v"(rw[u]));                \
        }                                                                       \
    }

// joint batch: both entities' loads issued before either's FMAs -> 2 chains
#define GATHER_BATCH8x2(S0A, JA, A0A, A1A, S0B, JB, A0B, A1B)                   \
    {                                                                           \
        uint2 qpa[4], qpb[4];                                                   \
        _Pragma("unroll")                                                       \
        for (int u = 0; u < 4; ++u) {                                           \
            qpa[u] = *reinterpret_cast<const uint2*>(&se[(S0A) + (JA) + 2 * u]);\
            qpb[u] = *reinterpret_cast<const uint2*>(&se[(S0B) + (JB) + 2 * u]);\
        }                                                                       \
        unsigned qsa[8], qsb[8];                                                \
        _Pragma("unroll")                                                       \
        for (int u = 0; u < 4; ++u) {                                           \
            qsa[2 * u]     = __builtin_amdgcn_readfirstlane(qpa[u].x);          \
            qsa[2 * u + 1] = __builtin_amdgcn_readfirstlane(qpa[u].y);          \
            qsb[2 * u]     = __builtin_amdgcn_readfirstlane(qpb[u].x);          \
            qsb[2 * u + 1] = __builtin_amdgcn_readfirstlane(qpb[u].y);          \
        }                                                                       \
        unsigned rwa[8], rwb_[8];                                               \
        _Pragma("unroll")                                                       \
        for (int u = 0; u < 8; ++u) {                                           \
            rwa[u] = *reinterpret_cast<const unsigned*>(                        \
                rwb + (size_t)((qsa[u] >> 16) & 0xFFFu) * 128 + loff);          \
            rwb_[u] = *reinterpret_cast<const unsigned*>(                       \
                rwb + (size_t)((qsb[u] >> 16) & 0xFFFu) * 128 + loff);          \
        }                                                                       \
        _Pragma("unroll")                                                       \
        for (int u = 0; u < 8; ++u) {                                           \
            asm("v_fma_mix_f32 %[d], %[s0], %[s1], %[d] op_sel:[0,0,0] op_sel_hi:[1,1,0]" \
                : [d]"+v"(A0A) : [s0]"s"(qsa[u]), [s1]"v"(rwa[u]));             \
            asm("v_fma_mix_f32 %[d], %[s0], %[s1], %[d] op_sel:[0,1,0] op_sel_hi:[1,1,0]" \
                : [d]"+v"(A1A) : [s0]"s"(qsa[u]), [s1]"v"(rwa[u]));             \
            asm("v_fma_mix_f32 %[d], %[s0], %[s1], %[d] op_sel:[0,0,0] op_sel_hi:[1,1,0]" \
                : [d]"+v"(A0B) : [s0]"s"(qsb[u]), [s1]"v"(rwb_[u]));            \
            asm("v_fma_mix_f32 %[d], %[s0], %[s1], %[d] op_sel:[0,1,0] op_sel_hi:[1,1,0]" \
                : [d]"+v"(A1B) : [s0]"s"(qsb[u]), [s1]"v"(rwb_[u]));            \
        }                                                                       \
    }

// ---------------------------------------------------------------------------
// Kernel 2: gather — one 512-thread block per 16-entity bucket.
// Phase A unchanged (r13). Phase B: the wave's TWO entities are processed in
// JOINT batches — both dependence chains (ds_read -> rfl -> load -> fma) are
// in flight simultaneously, doubling intra-wave ILP with zero added
// instructions (r10's rotation-copy trap avoided: all registers named).
// ---------------------------------------------------------------------------
__global__ __launch_bounds__(512) void gather_kernel(
    const unsigned* __restrict__ slots, const int* __restrict__ gcnt,
    const int* __restrict__ ovfcnt, const uint2* __restrict__ ovf,
    const _Float16* __restrict__ rwb, float* __restrict__ out,
    int NUMENT, int CAPB) {
    __shared__ unsigned se[SORTCAP];           // 18 KB sorted payloads
    __shared__ int cnt[EPB], basep[EPB];
    const int t = threadIdx.x;
    const int b = blockIdx.x;
    if (t < EPB) cnt[t] = 0;
    __syncthreads();

    int deg = gcnt[b];
    if (deg > CAPB) deg = CAPB;        // overflow entries went to ovf list
    const unsigned* sl = slots + (size_t)b * CAPB;

    // Phase A: coalesced load, LDS rank, hold in registers, sorted placement
    unsigned e[CPT];
    int rk[CPT];
#pragma unroll
    for (int u = 0; u < CPT; ++u) {
        const int k = t + u * 512;
        rk[u] = -1;
        if (k < deg) {
            e[u] = sl[k];
            rk[u] = atomicAdd(&cnt[(int)(e[u] >> 28)], 1);
        }
    }
    __syncthreads();
    if (t == 0) {
        int s = 0;
#pragma unroll
        for (int i = 0; i < EPB; ++i) { basep[i] = s; s += cnt[i]; }
    }
    __syncthreads();
#pragma unroll
    for (int u = 0; u < CPT; ++u)
        if (rk[u] >= 0) se[basep[(int)(e[u] >> 28)] + rk[u]] = e[u];
    __syncthreads();

    const int novf = min(*ovfcnt, OVFCAP);     // 0 in practice

    // Phase B: 8 waves x 2 entities, jointly batched
    const int wv = t >> 6, lane = t & 63;
    const int loff = lane * 2;                 // _Float16 element offset in row

    const int leA = wv * 2, leB = leA + 1;
    const int s0A = basep[leA], cA = cnt[leA];
    const int s0B = basep[leB], cB = cnt[leB];
    float a0A = 0.f, a1A = 0.f, a0B = 0.f, a1B = 0.f;
    int jA = 0, jB = 0;
    while (jA + 8 <= cA && jB + 8 <= cB) {
        GATHER_BATCH8x2(s0A, jA, a0A, a1A, s0B, jB, a0B, a1B);
        jA += 8; jB += 8;
    }
    for (; jA + 8 <= cA; jA += 8) GATHER_BATCH8(s0A, jA, a0A, a1A);
    for (; jB + 8 <= cB; jB += 8) GATHER_BATCH8(s0B, jB, a0B, a1B);
    for (; jA < cA; ++jA) {
        const unsigned q = se[s0A + jA];
        const unsigned qs = __builtin_amdgcn_readfirstlane(q);
        const unsigned rwv = *reinterpret_cast<const unsigned*>(
            rwb + (size_t)((qs >> 16) & 0xFFFu) * 128 + loff);
        asm("v_fma_mix_f32 %[d], %[s0], %[s1], %[d] op_sel:[0,0,0] op_sel_hi:[1,1,0]"
            : [d]"+v"(a0A) : [s0]"s"(qs), [s1]"v"(rwv));
        asm("v_fma_mix_f32 %[d], %[s0], %[s1], %[d] op_sel:[0,1,0] op_sel_hi:[1,1,0]"
            : [d]"+v"(a1A) : [s0]"s"(qs), [s1]"v"(rwv));
    }
    for (; jB < cB; ++jB) {
        const unsigned q = se[s0B + jB];
        const unsigned qs = __builtin_amdgcn_readfirstlane(q);
        const unsigned rwv = *reinterpret_cast<const unsigned*>(
            rwb + (size_t)((qs >> 16) & 0xFFFu) * 128 + loff);
        asm("v_fma_mix_f32 %[d], %[s0], %[s1], %[d] op_sel:[0,0,0] op_sel_hi:[1,1,0]"
            : [d]"+v"(a0B) : [s0]"s"(qs), [s1]"v"(rwv));
        asm("v_fma_mix_f32 %[d], %[s0], %[s1], %[d] op_sel:[0,1,0] op_sel_hi:[1,1,0]"
            : [d]"+v"(a1B) : [s0]"s"(qs), [s1]"v"(rwv));
    }
    // exact overflow contributions (novf == 0 in practice)
    for (int k = 0; k < novf; ++k) {
        const uint2 o = ovf[k];
        if ((int)(o.x >> 16) == b) {
            const int ole = (int)((o.x >> 12) & 15u);
            if (ole == leA || ole == leB) {
                const int orel = (int)(o.x & 0xFFFu);
                const float ov = __uint_as_float(o.y);
                const unsigned orw = *reinterpret_cast<const unsigned*>(
                    rwb + (size_t)orel * 128 + loff);
                const half2v oh = __builtin_bit_cast(half2v, orw);
                if (ole == leA) { a0A += ov * (float)oh[0]; a1A += ov * (float)oh[1]; }
                else            { a0B += ov * (float)oh[0]; a1B += ov * (float)oh[1]; }
            }
        }
    }
    {
        const int ventA = b * EPB + leA;
        if (ventA < NUMENT) {
            float* op = out + (size_t)ventA * 128 + loff;
            float2 o2; o2.x = fmaxf(a0A, 0.f); o2.y = fmaxf(a1A, 0.f);
            *reinterpret_cast<float2*>(op) = o2;
        }
        const int ventB = b * EPB + leB;
        if (ventB < NUMENT) {
            float* op = out + (size_t)ventB * 128 + loff;
            float2 o2; o2.x = fmaxf(a0B, 0.f); o2.y = fmaxf(a1B, 0.f);
            *reinterpret_cast<float2*>(op) = o2;
        }
    }
}

// ---------------------------------------------------------------------------
// Fallback path (ws too small / shape out of range): direct vector scatter.
// ---------------------------------------------------------------------------
__global__ void rwb_f32_kernel(const float* __restrict__ rel, const float* __restrict__ W,
                               const float* __restrict__ b, float* __restrict__ rwb, int R) {
    const int k = blockIdx.x;
    const int n = threadIdx.x;
    __shared__ float relk[128];
    relk[n] = rel[(size_t)k * 128 + n];
    __syncthreads();
    const float4* w4 = reinterpret_cast<const float4*>(W + (size_t)n * 128);
    const float4* r4 = reinterpret_cast<const float4*>(relk);
    float acc = 0.f;
#pragma unroll
    for (int i = 0; i < 32; ++i) {
        float4 a = r4[i], w = w4[i];
        acc += a.x * w.x + a.y * w.y + a.z * w.z + a.w * w.w;
    }
    rwb[(size_t)k * 128 + n] = acc + b[n];
}

__global__ void scatter_vec_kernel(const int* __restrict__ heads, const int* __restrict__ tails,
                                   const int* __restrict__ rels, const float* __restrict__ val,
                                   const float* __restrict__ rwb, float* __restrict__ out,
                                   long long nitems) {
    const long long i = (long long)blockIdx.x * blockDim.x + threadIdx.x;
    if (i >= nitems) return;
    const int e = (int)(i >> 5);
    const int c = (int)(i & 31) * 4;
    const float v = val[e];
    float4 rw = *reinterpret_cast<const float4*>(rwb + (size_t)rels[e] * 128 + c);
    float* pt = out + (size_t)tails[e] * 128 + c;
    float* ph = out + (size_t)heads[e] * 128 + c;
    unsafeAtomicAdd(pt + 0, v * rw.x); unsafeAtomicAdd(pt + 1, v * rw.y);
    unsafeAtomicAdd(pt + 2, v * rw.z); unsafeAtomicAdd(pt + 3, v * rw.w);
    unsafeAtomicAdd(ph + 0, v * rw.x); unsafeAtomicAdd(ph + 1, v * rw.y);
    unsafeAtomicAdd(ph + 2, v * rw.z); unsafeAtomicAdd(ph + 3, v * rw.w);
}

__global__ void relu_kernel(float* __restrict__ out, int n4) {
    const int i = blockIdx.x * blockDim.x + threadIdx.x;
    if (i >= n4) return;
    float4* p = reinterpret_cast<float4*>(out) + i;
    float4 v = *p;
    v.x = fmaxf(v.x, 0.f); v.y = fmaxf(v.y, 0.f);
    v.z = fmaxf(v.z, 0.f); v.w = fmaxf(v.w, 0.f);
    *p = v;
}

// ---------------------------------------------------------------------------
extern "C" void kernel_launch(void* const* d_in, const int* in_sizes, int n_in,
                              void* d_out, int out_size, void* d_ws, size_t ws_size,
                              hipStream_t stream) {
    // inputs: 0 local_entity [B*M] (shape only), 1 heads [E], 2 tails [E],
    //         3 rels [E], 4 val [E], 5 rel_features [R*D], 6 W [D*D], 7 b [D]
    const int* heads = (const int*)d_in[1];
    const int* tails = (const int*)d_in[2];
    const int* rels  = (const int*)d_in[3];
    const float* val  = (const float*)d_in[4];
    const float* relf = (const float*)d_in[5];
    const float* W    = (const float*)d_in[6];
    const float* b    = (const float*)d_in[7];
    float* out = (float*)d_out;

    const int NUMENT = in_sizes[0];          // 16000
    const int E      = in_sizes[1];          // 2,000,000
    const int D      = in_sizes[7];          // 128
    const int R      = in_sizes[5] / D;      // 2000

    const int NB = (NUMENT + EPB - 1) / EPB; // 1000 buckets
    const long long mean = (2LL * E * EPB) / (NUMENT > 0 ? NUMENT : 1);
    int CAPB = (int)(mean + mean / 16 + 256);

    // ws layout: rwb | ctrl { gcnt[NB], ovfcnt } | ovf[OVFCAP] | slots
    const size_t rwb_bytes = (size_t)R * D * sizeof(_Float16);          // 512 KB
    const size_t off_ctrl  = (rwb_bytes + 255) & ~(size_t)255;
    const size_t ctrl_b    = (size_t)(NB + 1) * sizeof(int);
    const size_t off_ovf   = (off_ctrl + ctrl_b + 255) & ~(size_t)255;
    const size_t ovf_b     = (size_t)OVFCAP * sizeof(uint2);            // 512 KB
    const size_t off_slots = (off_ovf + ovf_b + 255) & ~(size_t)255;
    const size_t slots_b   = (size_t)NB * CAPB * sizeof(unsigned);      // ~18 MB

    if (NB <= MAXNB && R < 4096 && CAPB <= SORTCAP &&
        ws_size >= off_slots + slots_b) {
        _Float16* rwb   = (_Float16*)d_ws;
        int* gcnt       = (int*)((char*)d_ws + off_ctrl);
        int* ovfcnt     = gcnt + NB;
        uint2* ovf      = (uint2*)((char*)d_ws + off_ovf);
        unsigned* slots = (unsigned*)((char*)d_ws + off_slots);

        hipMemsetAsync(gcnt, 0, ctrl_b, stream);     // gcnt + ovfcnt (4 KB)
        bin_rwb_kernel<<<(E + FPB - 1) / FPB, 1024, 0, stream>>>(
            heads, tails, rels, val, relf, W, b, rwb,
            gcnt, ovfcnt, ovf, slots, E, R, NB, CAPB);
        gather_kernel<<<NB, 512, 0, stream>>>(
            slots, gcnt, ovfcnt, ovf, rwb, out, NUMENT, CAPB);
    } else {
        // fallback: accumulate directly into out (slow but small-ws safe)
        float* rwb = (float*)d_ws;           // R*D fp32 (~1 MB)
        hipMemsetAsync(out, 0, (size_t)out_size * sizeof(float), stream);
        rwb_f32_kernel<<<R, 128, 0, stream>>>(relf, W, b, rwb, R);
        const long long items = (long long)E * 32;
        scatter_vec_kernel<<<(unsigned)((items + 255) / 256), 256, 0, stream>>>(
            heads, tails, rels, val, rwb, out, items);
        relu_kernel<<<(out_size / 4 + 255) / 256, 256, 0, stream>>>(out, out_size / 4);
    }
}